// Round 1
// baseline (11.713 us; speedup 1.0000x reference)
//
#include <hip/hip_runtime.h>
#include <math.h>

// LocalDists: for each point n in [0,N), distances to the 2K band neighbors
// (n-K..n-1, n+1..n+K), invalid -> inf -> sorted to end -> 0. Output sorted
// ascending per position. x: [B, N, 3] f32. out: [B, N*2K] f32 (flat).

#define KNB 16            // neighbors per side
#define NBAND (2 * KNB)   // 32
#define BLK 256

#define SENTINEL 1.0e30f

__global__ __launch_bounds__(BLK) void band_knn_kernel(
    const float* __restrict__ x, float* __restrict__ out, int N) {
    const int b = blockIdx.y;
    const int base = blockIdx.x * BLK;       // first position this block owns
    const int tid = threadIdx.x;
    const int n = base + tid;                // this thread's position

    // Stage points [base-K, base+BLK+K) of this batch into LDS.
    __shared__ float sx[(BLK + 2 * KNB) * 3];
    const float* xb = x + (size_t)b * N * 3;
    const int stage_elems = (BLK + 2 * KNB) * 3;  // 864 floats
    for (int i = tid; i < stage_elems; i += BLK) {
        int p = base - KNB + i / 3;
        int c = i - (i / 3) * 3;
        float val = 0.0f;
        if (p >= 0 && p < N) val = xb[(size_t)p * 3 + c];
        sx[i] = val;
    }
    __syncthreads();

    // Center point.
    const int ci = (tid + KNB) * 3;
    const float cx = sx[ci + 0];
    const float cy = sx[ci + 1];
    const float cz = sx[ci + 2];

    // 32 band distances (invalid -> sentinel).
    float v[NBAND];
#pragma unroll
    for (int j = 0; j < NBAND; ++j) {
        const int off = (j < KNB) ? (j - KNB) : (j - KNB + 1);  // -16..-1,1..16
        const int m = n + off;
        const int li = (tid + KNB + off) * 3;
        const float dx = cx - sx[li + 0];
        const float dy = cy - sx[li + 1];
        const float dz = cz - sx[li + 2];
        const float d = sqrtf(dx * dx + dy * dy + dz * dz);
        v[j] = (m >= 0 && m < N) ? d : SENTINEL;
    }

    // Bitonic sort, ascending, fully unrolled (all indices compile-time).
#pragma unroll
    for (int kk = 2; kk <= NBAND; kk <<= 1) {
#pragma unroll
        for (int jj = kk >> 1; jj > 0; jj >>= 1) {
#pragma unroll
            for (int i = 0; i < NBAND; ++i) {
                const int l = i ^ jj;
                if (l > i) {
                    const bool up = ((i & kk) == 0);
                    const float a = v[i], c = v[l];
                    const float mn = fminf(a, c);
                    const float mx = fmaxf(a, c);
                    v[i] = up ? mn : mx;
                    v[l] = up ? mx : mn;
                }
            }
        }
    }

    // Sentinels (invalid neighbors) -> 0, vectorized store.
    float* o = out + ((size_t)b * N + n) * NBAND;
    float4* o4 = reinterpret_cast<float4*>(o);
#pragma unroll
    for (int i = 0; i < NBAND / 4; ++i) {
        float4 w;
        w.x = (v[4 * i + 0] >= SENTINEL) ? 0.0f : v[4 * i + 0];
        w.y = (v[4 * i + 1] >= SENTINEL) ? 0.0f : v[4 * i + 1];
        w.z = (v[4 * i + 2] >= SENTINEL) ? 0.0f : v[4 * i + 2];
        w.w = (v[4 * i + 3] >= SENTINEL) ? 0.0f : v[4 * i + 3];
        o4[i] = w;
    }
}

extern "C" void kernel_launch(void* const* d_in, const int* in_sizes, int n_in,
                              void* d_out, int out_size, void* d_ws, size_t ws_size,
                              hipStream_t stream) {
    const float* x = (const float*)d_in[0];
    float* out = (float*)d_out;
    const int B = 4;
    const int N = in_sizes[0] / (B * 3);   // 8192
    dim3 grid(N / BLK, B);
    band_knn_kernel<<<grid, dim3(BLK), 0, stream>>>(x, out, N);
}